// Round 1
// baseline (281.673 us; speedup 1.0000x reference)
//
#include <hip/hip_runtime.h>

// KPN per-pixel dynamic kernel conv.
// data:    [1, 8, 3, 96, 96]        fp32 (~0.9 MB)
// kernels: [1, 8, 225, 3, 96, 96]   fp32 (199 MB streaming read, used once)
// out:     [1, 8, 3, 96, 96]        fp32
// out[t,c,h,w] = sum_{i,j} kernels[t,i*15+j,c,h,w] * data[t,c,h+i-7,w+j-7] (zero pad)
//
// Round 7: in-block tap-row split. 4 waves per block share the same 64 output
// quads; wave w streams tap rows {4w..4w+3} (wave 3: 3 rows) with NT dwordx4
// loads and its own double-buffer, then a 3 KB bank-conflict-free LDS reduce
// combines the partials. Rationale: previous 1-wave blocks ran at 0.85
// waves/SIMD -> ~500 cycles of exposed NT-HBM latency per tap row and an 18%
// 4-vs-3 blocks/CU finishing tail. Same total HBM traffic (199 MB, NT: no
// dirty-poison L3 write-backs), 4x wave parallelism, per-wave work quartered.

typedef float vf4 __attribute__((ext_vector_type(4)));

constexpr int K  = 15;
constexpr int P  = 7;
constexpr int H  = 96;
constexpr int W  = 96;
constexpr int C  = 3;
constexpr int T  = 8;
constexpr int HW = H * W;              // 9216
constexpr int K2 = K * K;              // 225
constexpr int NP = T * C;              // 24 planes
constexpr int NE = NP * HW;            // 221184 output elems
constexpr size_t CHW = (size_t)C * HW; // 27648 floats between consecutive taps
constexpr int NQ   = NE / 4;           // 55296 quads
constexpr int QPB  = 64;               // quads per block (one wave-width)
constexpr int BLK  = 256;              // 4 waves per block
constexpr int NBLK = NQ / QPB;         // 864 blocks

__device__ __forceinline__ vf4 nt4(const float* p) {
    return __builtin_nontemporal_load(reinterpret_cast<const vf4*>(p));
}

__global__ __launch_bounds__(BLK) void kpn_split4(
    const float* __restrict__ data,
    const float* __restrict__ kern,
    float* __restrict__ out)
{
    const int lane  = threadIdx.x & 63;
    const int wave  = threadIdx.x >> 6;
    const int q     = blockIdx.x * QPB + lane;    // quad id (same for all 4 waves)
    const int w4    = q % (W / 4);
    const int rem   = q / (W / 4);
    const int h     = rem % H;
    const int plane = rem / H;          // t*C + c
    const int t     = plane / C;
    const int c     = plane % C;
    const int col   = w4 * 4;

    // tap (i,j) lives at kbase + (i*K + j)*CHW
    const float* __restrict__ kbase =
        kern + ((size_t)(t * K2) * C + (size_t)c) * HW + (size_t)h * W + col;
    const float* __restrict__ dpl = data + plane * HW;

    // Column clamp/validity is row-independent: precompute once.
    int  colc[K + 3];
    bool cval[K + 3];
    #pragma unroll
    for (int m = 0; m < K + 3; ++m) {
        const int cc = col - P + m;
        cval[m] = (cc >= 0) && (cc < W);
        colc[m] = (cc < 0) ? 0 : ((cc >= W) ? (W - 1) : cc);
    }

    float acc[4] = {0.f, 0.f, 0.f, 0.f};

    auto load_row = [&](vf4 (&buf)[K], int i) {
        const float* p = kbase + (size_t)(i * K) * CHW;
        #pragma unroll
        for (int j = 0; j < K; ++j) buf[j] = nt4(p + (size_t)j * CHW);
    };

    auto consume_row = [&](vf4 (&buf)[K], int i) {
        const int srow = h + i - P;
        const bool rv  = (srow >= 0) && (srow < H);
        const float* __restrict__ drow = dpl + (rv ? srow : 0) * W;
        float dwin[K + 3];
        #pragma unroll
        for (int m = 0; m < K + 3; ++m) {
            const float v = drow[colc[m]];           // address always in-bounds
            dwin[m] = (rv && cval[m]) ? v : 0.f;
        }
        #pragma unroll
        for (int j = 0; j < K; ++j) {
            acc[0] += buf[j][0] * dwin[j + 0];
            acc[1] += buf[j][1] * dwin[j + 1];
            acc[2] += buf[j][2] * dwin[j + 2];
            acc[3] += buf[j][3] * dwin[j + 3];
        }
    };

    // Wave w owns tap rows [4w, 4w+nr): 4/4/4/3 split of K=15.
    const int r0 = wave * 4;
    vf4 A[K], Bv[K];
    // Double-buffered pipeline over (at most) 4 rows; 30 NT loads in flight
    // before the first consume. All branches are wave-uniform.
    load_row(A, r0);
    load_row(Bv, r0 + 1);                 // wave 3: row 13, valid
    consume_row(A, r0);
    load_row(A, r0 + 2);                  // wave 3: row 14, valid
    consume_row(Bv, r0 + 1);
    if (wave != 3) load_row(Bv, r0 + 3);
    consume_row(A, r0 + 2);
    if (wave != 3) consume_row(Bv, r0 + 3);

    // Reduce the 4 wave partials. [part][comp][lane] layout: lane-stride 4 B
    // -> bank-conflict-free scalar ds_write/ds_read.
    __shared__ float red[3][4][QPB];
    if (wave != 0) {
        red[wave - 1][0][lane] = acc[0];
        red[wave - 1][1][lane] = acc[1];
        red[wave - 1][2][lane] = acc[2];
        red[wave - 1][3][lane] = acc[3];
    }
    __syncthreads();
    if (wave == 0) {
        #pragma unroll
        for (int wv = 0; wv < 3; ++wv) {
            acc[0] += red[wv][0][lane];
            acc[1] += red[wv][1][lane];
            acc[2] += red[wv][2][lane];
            acc[3] += red[wv][3][lane];
        }
        vf4 o = { acc[0], acc[1], acc[2], acc[3] };
        float* op = out + (size_t)plane * HW + (size_t)h * W + col;
        __builtin_nontemporal_store(o, reinterpret_cast<vf4*>(op));
    }
}

extern "C" void kernel_launch(void* const* d_in, const int* in_sizes, int n_in,
                              void* d_out, int out_size, void* d_ws, size_t ws_size,
                              hipStream_t stream) {
    const float* data = (const float*)d_in[0];
    const float* kern = (const float*)d_in[1];
    float* out        = (float*)d_out;
    hipLaunchKernelGGL(kpn_split4, dim3(NBLK), dim3(BLK), 0, stream,
                       data, kern, out);
}

// Round 2
// 277.331 us; speedup vs baseline: 1.0157x; 1.0157x over previous
//
#include <hip/hip_runtime.h>

// KPN per-pixel dynamic kernel conv.
// data:    [1, 8, 3, 96, 96]        fp32 (~0.9 MB)
// kernels: [1, 8, 225, 3, 96, 96]   fp32 (199 MB streaming read, used once)
// out:     [1, 8, 3, 96, 96]        fp32
// out[t,c,h,w] = sum_{i,j} kernels[t,i*15+j,c,h,w] * data[t,c,h+i-7,w+j-7] (zero pad)
//
// Round 8: REVERT to the round-6 single-wave fused kernel (best measured:
// 275.3/277.5 us). Round-7's 4-wave tap-split was neutral on the kernel
// portion (+LDS reduce cost, no latency win): the stream was already
// throughput-bound, not latency-bound (50-100 KB in flight per CU vs ~9 KB
// needed). Remaining gap to the compound floor (2 harness poison fills
// ~237 us @ 84% HBM peak + 199 MB mandatory NT stream ~32 us) is ~3%.
// Nontemporal loads avoid L2/L3 allocation -> no dirty-poison write-backs.
// 864 one-wave blocks; no LDS / barriers / atomics -> bit-deterministic.

typedef float vf4 __attribute__((ext_vector_type(4)));

constexpr int K  = 15;
constexpr int P  = 7;
constexpr int H  = 96;
constexpr int W  = 96;
constexpr int C  = 3;
constexpr int T  = 8;
constexpr int HW = H * W;              // 9216
constexpr int K2 = K * K;              // 225
constexpr int NP = T * C;              // 24 planes
constexpr int NE = NP * HW;            // 221184 output elems
constexpr size_t CHW = (size_t)C * HW; // 27648 floats between consecutive taps
constexpr int NQ   = NE / 4;           // 55296 quads
constexpr int BLK  = 64;               // one wave per block
constexpr int NBLK = NQ / BLK;         // 864 blocks

__device__ __forceinline__ vf4 nt4(const float* p) {
    return __builtin_nontemporal_load(reinterpret_cast<const vf4*>(p));
}

__global__ __launch_bounds__(BLK) void kpn_fused_nt(
    const float* __restrict__ data,
    const float* __restrict__ kern,
    float* __restrict__ out)
{
    const int q     = blockIdx.x * BLK + threadIdx.x;   // quad id
    const int w4    = q % (W / 4);
    const int rem   = q / (W / 4);
    const int h     = rem % H;
    const int plane = rem / H;          // t*C + c
    const int t     = plane / C;
    const int c     = plane % C;
    const int col   = w4 * 4;

    // tap (i,j) lives at kbase + (i*K + j)*CHW
    const float* __restrict__ kbase =
        kern + ((size_t)(t * K2) * C + (size_t)c) * HW + (size_t)h * W + col;
    const float* __restrict__ dpl = data + plane * HW;

    // Column clamp/validity is row-independent: precompute once.
    int  colc[K + 3];
    bool cval[K + 3];
    #pragma unroll
    for (int m = 0; m < K + 3; ++m) {
        const int cc = col - P + m;
        cval[m] = (cc >= 0) && (cc < W);
        colc[m] = (cc < 0) ? 0 : ((cc >= W) ? (W - 1) : cc);
    }

    float acc[4] = {0.f, 0.f, 0.f, 0.f};

    auto load_row = [&](vf4 (&buf)[K], int i) {
        const float* p = kbase + (size_t)(i * K) * CHW;
        #pragma unroll
        for (int j = 0; j < K; ++j) buf[j] = nt4(p + (size_t)j * CHW);
    };

    auto consume_row = [&](vf4 (&buf)[K], int i) {
        const int srow = h + i - P;
        const bool rv  = (srow >= 0) && (srow < H);
        const float* __restrict__ drow = dpl + (rv ? srow : 0) * W;
        float dwin[K + 3];
        #pragma unroll
        for (int m = 0; m < K + 3; ++m) {
            const float v = drow[colc[m]];           // address always in-bounds
            dwin[m] = (rv && cval[m]) ? v : 0.f;
        }
        #pragma unroll
        for (int j = 0; j < K; ++j) {
            acc[0] += buf[j][0] * dwin[j + 0];
            acc[1] += buf[j][1] * dwin[j + 1];
            acc[2] += buf[j][2] * dwin[j + 2];
            acc[3] += buf[j][3] * dwin[j + 3];
        }
    };

    vf4 A[K], B[K];
    load_row(A, 0);
    #pragma unroll 1
    for (int i = 0; i < K - 1; i += 2) {     // i = 0,2,...,12
        load_row(B, i + 1);
        consume_row(A, i);
        load_row(A, i + 2);                  // i+2 <= 14: always a valid row
        consume_row(B, i + 1);
    }
    consume_row(A, K - 1);

    vf4 o = { acc[0], acc[1], acc[2], acc[3] };
    float* op = out + (size_t)plane * HW + (size_t)h * W + col;
    __builtin_nontemporal_store(o, reinterpret_cast<vf4*>(op));
}

extern "C" void kernel_launch(void* const* d_in, const int* in_sizes, int n_in,
                              void* d_out, int out_size, void* d_ws, size_t ws_size,
                              hipStream_t stream) {
    const float* data = (const float*)d_in[0];
    const float* kern = (const float*)d_in[1];
    float* out        = (float*)d_out;
    hipLaunchKernelGGL(kpn_fused_nt, dim3(NBLK), dim3(BLK), 0, stream,
                       data, kern, out);
}